// Round 1
// baseline (6259.233 us; speedup 1.0000x reference)
//
#include <hip/hip_runtime.h>
#include <math.h>

#define NN 4096

// ---------------- cols precompute: per-type masked column sums of W ----------
// part[(c*6+t)*NN + j] = sum over rows i in chunk c of W[i,j] where Ty[i,j]==t+1
__global__ __launch_bounds__(256) void col_partial_k(
    const float* __restrict__ W, const int* __restrict__ Ty,
    float* __restrict__ part, int chunkRows)
{
    const int j = blockIdx.x * 256 + threadIdx.x;
    const int c = blockIdx.y;
    const size_t i0 = (size_t)c * (size_t)chunkRows;
    float a0 = 0.f, a1 = 0.f, a2 = 0.f, a3 = 0.f, a4 = 0.f, a5 = 0.f;
    for (size_t i = i0; i < i0 + (size_t)chunkRows; ++i) {
        const size_t off = i * NN + j;
        const float w = W[off];
        const int t = Ty[off];
        a0 += (t == 1) ? w : 0.f;
        a1 += (t == 2) ? w : 0.f;
        a2 += (t == 3) ? w : 0.f;
        a3 += (t == 4) ? w : 0.f;
        a4 += (t == 5) ? w : 0.f;
        a5 += (t == 6) ? w : 0.f;
    }
    const size_t base = ((size_t)c * 6) * NN + (size_t)j;
    part[base + 0 * NN] = a0;
    part[base + 1 * NN] = a1;
    part[base + 2 * NN] = a2;
    part[base + 3 * NN] = a3;
    part[base + 4 * NN] = a4;
    part[base + 5 * NN] = a5;
}

__global__ __launch_bounds__(256) void col_reduce_k(
    const float* __restrict__ part, float* __restrict__ cols, int CH)
{
    const int idx = blockIdx.x * 256 + threadIdx.x; // t*NN + j
    float s = 0.f;
    for (int c = 0; c < CH; ++c) s += part[(size_t)c * 6 * NN + idx];
    cols[idx] = s;
}

// ---------------- main simulation: single workgroup, 512 thr x 8 neurons ----
__global__ __launch_bounds__(512) void hh_sim_k(
    const float* __restrict__ Iext, const float* __restrict__ V0,
    const float* __restrict__ m0, const float* __restrict__ h0,
    const float* __restrict__ n0, const float* __restrict__ s0,
    const float* __restrict__ colsg, const int* __restrict__ Tp,
    const float* __restrict__ W, const int* __restrict__ Ty,
    int computeCols, float* __restrict__ out)
{
#pragma clang fp contract(off)
    const int tid = threadIdx.x;      // 0..511
    const int j0 = tid * 8;           // 8 contiguous neurons per thread
    const int steps = Tp[0] * 100;    // T / DT, DT = 0.01

    const float E[6]   = { 0.0f, -70.0f, -90.0f, 0.0f, 0.0f, 0.0f };
    const float tau[6] = { 2.0f, 5.0f, 10.0f, 100.0f, 50.0f, 30.0f };
    float dec[6];
#pragma unroll
    for (int t = 0; t < 6; ++t) dec[t] = 1.0f - 0.01f / tau[t];
    // SIGN = {-1,+1,+1,-1,-1,-1}

    float cw[6][8];
    if (computeCols) {
        // tiny-workspace fallback: each thread column-sums its own 8 columns
        float acc[6][8];
#pragma unroll
        for (int t = 0; t < 6; ++t)
#pragma unroll
            for (int r = 0; r < 8; ++r) acc[t][r] = 0.f;
        for (int i = 0; i < NN; ++i) {
            const size_t rowo = (size_t)i * NN + (size_t)j0;
#pragma unroll
            for (int r = 0; r < 8; ++r) {
                const float w = W[rowo + r];
                const int t = Ty[rowo + r];
                acc[0][r] += (t == 1) ? w : 0.f;
                acc[1][r] += (t == 2) ? w : 0.f;
                acc[2][r] += (t == 3) ? w : 0.f;
                acc[3][r] += (t == 4) ? w : 0.f;
                acc[4][r] += (t == 5) ? w : 0.f;
                acc[5][r] += (t == 6) ? w : 0.f;
            }
        }
#pragma unroll
        for (int t = 0; t < 6; ++t)
#pragma unroll
            for (int r = 0; r < 8; ++r) cw[t][r] = acc[t][r];
    } else {
#pragma unroll
        for (int t = 0; t < 6; ++t)
#pragma unroll
            for (int r = 0; r < 8; ++r)
                cw[t][r] = colsg[(size_t)t * NN + j0 + r];
    }

    float V[8], m[8], h[8], n[8], Ie[8], s[6][8];
#pragma unroll
    for (int r = 0; r < 8; ++r) {
        V[r] = V0[j0 + r];
        m[r] = m0[j0 + r];
        h[r] = h0[j0 + r];
        n[r] = n0[j0 + r];
        Ie[r] = Iext[j0 + r];
    }
#pragma unroll
    for (int t = 0; t < 6; ++t)
#pragma unroll
        for (int r = 0; r < 8; ++r) s[t][r] = s0[(size_t)t * NN + j0 + r];

    __shared__ float wsum[8];
    __shared__ float Ssh;

    for (int k = 0; k < steps; ++k) {
        // --- coupling partial: sum_t sign_t * sum_j (G*s)*(V-E_t)*cols ---
        float p = 0.f;
#pragma unroll
        for (int r = 0; r < 8; ++r) {
            const float v = V[r];
#pragma unroll
            for (int t = 0; t < 6; ++t) {
                s[t][r] = s[t][r] * dec[t];                 // s *= decay (pre-use)
                const float vec = (0.1f * s[t][r]) * (v - E[t]);
                const float term = vec * cw[t][r];
                if (t == 1 || t == 2) p += term; else p -= term;
            }
        }
        // wave (64-lane) reduction, then cross-wave via LDS
#pragma unroll
        for (int off = 32; off > 0; off >>= 1) p += __shfl_down(p, off);
        if ((tid & 63) == 0) wsum[tid >> 6] = p;
        __syncthreads();
        if (tid == 0) {
            float S = 0.f;
            for (int w2 = 0; w2 < 8; ++w2) S += wsum[w2];
            Ssh = S;
        }
        __syncthreads();
        const float S = Ssh;

        // --- per-neuron HH update (IEEE semantics; NaN/inf flow matters) ---
#pragma unroll
        for (int r = 0; r < 8; ++r) {
            const float v = V[r];
            const float Ipre = Ie[r] + S;
            const float am = (2.5f - 0.1f * v) / (expf(2.5f - 0.1f * v) - 1.0f);
            const float bm = 4.0f * expf((-v) / 18.0f);
            const float ah = 0.07f * expf((-v) / 20.0f);
            const float bh = 1.0f / (expf(3.0f - 0.1f * v) + 1.0f);
            const float an = (0.1f - 0.01f * v) / (expf(1.0f - 0.1f * v) - 1.0f);
            const float bn = 0.125f * expf((-v) / 80.0f);
            const float mm = m[r] + 0.01f * (am * (1.0f - m[r]) - bm * m[r]);
            const float hh = h[r] + 0.01f * (ah * (1.0f - h[r]) - bh * h[r]);
            const float nn = n[r] + 0.01f * (an * (1.0f - n[r]) - bn * n[r]);
            m[r] = mm; h[r] = hh; n[r] = nn;
            const float INa = ((120.0f * ((mm * mm) * mm)) * hh) * (v - 50.0f);
            const float n2 = nn * nn;
            const float IK = (36.0f * (n2 * n2)) * (v + 77.0f);
            const float IL = 0.3f * (v + 54.387f);
            const float u = v + 0.01f * (((Ipre - INa) - IK) - IL);
            // clip then nan_to_num: numpy clip propagates NaN -> 0
            V[r] = (u != u) ? 0.0f : fminf(fmaxf(u, -100.0f), 100.0f);
        }

        // --- write V_hist row k (two float4 per thread, coalesced) ---
        float4* o = (float4*)(out + (size_t)k * NN + j0);
        o[0] = make_float4(V[0], V[1], V[2], V[3]);
        o[1] = make_float4(V[4], V[5], V[6], V[7]);
    }
}

extern "C" void kernel_launch(void* const* d_in, const int* in_sizes, int n_in,
                              void* d_out, int out_size, void* d_ws, size_t ws_size,
                              hipStream_t stream)
{
    const float* Iext = (const float*)d_in[0];
    const float* W    = (const float*)d_in[1];
    const float* V0   = (const float*)d_in[2];
    const float* m0   = (const float*)d_in[3];
    const float* h0   = (const float*)d_in[4];
    const float* n0   = (const float*)d_in[5];
    const float* s0   = (const float*)d_in[6];
    const int*   Ty   = (const int*)d_in[7];
    const int*   Tp   = (const int*)d_in[8];
    float* out = (float*)d_out;
    float* ws  = (float*)d_ws;

    const size_t needCH8 = (size_t)(8 * 6 + 6) * NN * sizeof(float); // ~864 KB
    const size_t needCH1 = (size_t)6 * NN * sizeof(float);           // 96 KB

    if (ws_size >= needCH8) {
        float* part = ws;
        float* cols = ws + (size_t)8 * 6 * NN;
        hipLaunchKernelGGL(col_partial_k, dim3(NN / 256, 8), dim3(256), 0, stream,
                           W, Ty, part, NN / 8);
        hipLaunchKernelGGL(col_reduce_k, dim3(6 * NN / 256), dim3(256), 0, stream,
                           part, cols, 8);
        hipLaunchKernelGGL(hh_sim_k, dim3(1), dim3(512), 0, stream,
                           Iext, V0, m0, h0, n0, s0, cols, Tp, W, Ty, 0, out);
    } else if (ws_size >= needCH1) {
        // single-chunk: part layout with c=0 IS the cols layout
        float* cols = ws;
        hipLaunchKernelGGL(col_partial_k, dim3(NN / 256, 1), dim3(256), 0, stream,
                           W, Ty, cols, NN);
        hipLaunchKernelGGL(hh_sim_k, dim3(1), dim3(512), 0, stream,
                           Iext, V0, m0, h0, n0, s0, cols, Tp, W, Ty, 0, out);
    } else {
        // pathological tiny workspace: compute cols inside the sim kernel
        hipLaunchKernelGGL(hh_sim_k, dim3(1), dim3(512), 0, stream,
                           Iext, V0, m0, h0, n0, s0, (const float*)0, Tp, W, Ty, 1, out);
    }
}

// Round 2
// 2258.446 us; speedup vs baseline: 2.7715x; 2.7715x over previous
//
#include <hip/hip_runtime.h>
#include <math.h>

#define NN 4096

// ---------------- cols precompute: per-type masked column sums of W ----------
// part[(c*6+t)*NN + j] = sum over rows i in chunk c of W[i,j] where Ty[i,j]==t+1
__global__ __launch_bounds__(256) void col_partial_k(
    const float* __restrict__ W, const int* __restrict__ Ty,
    float* __restrict__ part, int chunkRows)
{
    const int j = blockIdx.x * 256 + threadIdx.x;
    const int c = blockIdx.y;
    const size_t i0 = (size_t)c * (size_t)chunkRows;
    float a0 = 0.f, a1 = 0.f, a2 = 0.f, a3 = 0.f, a4 = 0.f, a5 = 0.f;
#pragma unroll 4
    for (size_t i = i0; i < i0 + (size_t)chunkRows; ++i) {
        const size_t off = i * NN + j;
        const float w = W[off];
        const int t = Ty[off];
        a0 += (t == 1) ? w : 0.f;
        a1 += (t == 2) ? w : 0.f;
        a2 += (t == 3) ? w : 0.f;
        a3 += (t == 4) ? w : 0.f;
        a4 += (t == 5) ? w : 0.f;
        a5 += (t == 6) ? w : 0.f;
    }
    const size_t base = ((size_t)c * 6) * NN + (size_t)j;
    part[base + 0 * NN] = a0;
    part[base + 1 * NN] = a1;
    part[base + 2 * NN] = a2;
    part[base + 3 * NN] = a3;
    part[base + 4 * NN] = a4;
    part[base + 5 * NN] = a5;
}

__global__ __launch_bounds__(256) void col_reduce_k(
    const float* __restrict__ part, float* __restrict__ cols, int CH)
{
    const int idx = blockIdx.x * 256 + threadIdx.x; // t*NN + j
    float s = 0.f;
    for (int c = 0; c < CH; ++c) s += part[(size_t)c * 6 * NN + idx];
    cols[idx] = s;
}

// ---------------- main simulation: single workgroup, 512 thr x 8 neurons ----
// Key algebraic fact: s has NO V-dependence -> s_k = s0 * dec^(k+1).
// S(k) = sum_t sign_t * D_t * ( sum_j q_tj * V_j  -  E_t * B_t ),
//   q_tj = 0.1 * s0_tj * cols_tj   (per-thread constant),
//   D_t  = dec_t^(k+1)             (running scalar, identical in all threads),
//   B_t  = sum_j q_tj              (block-reduced once; only t=1,2 have E!=0).
__global__ __launch_bounds__(512) void hh_sim_k(
    const float* __restrict__ Iext, const float* __restrict__ V0,
    const float* __restrict__ m0, const float* __restrict__ h0,
    const float* __restrict__ n0, const float* __restrict__ s0,
    const float* __restrict__ colsg, const int* __restrict__ Tp,
    const float* __restrict__ W, const int* __restrict__ Ty,
    int computeCols, float* __restrict__ out)
{
#pragma clang fp contract(off)
    const int tid = threadIdx.x;      // 0..511
    const int j0 = tid * 8;           // 8 contiguous neurons per thread
    const int steps = Tp[0] * 100;    // T / DT, DT = 0.01

    const float tau[6] = { 2.0f, 5.0f, 10.0f, 100.0f, 50.0f, 30.0f };
    const float sgn[6] = { -1.0f, 1.0f, 1.0f, -1.0f, -1.0f, -1.0f };
    float dec[6], sD[6];
#pragma unroll
    for (int t = 0; t < 6; ++t) { dec[t] = 1.0f - 0.01f / tau[t]; sD[t] = sgn[t]; }

    // ---- q = 0.1 * s0 * cols (cols from global, or computed here if no ws) --
    float q[6][8];
    if (computeCols) {
        float acc[6][8];
#pragma unroll
        for (int t = 0; t < 6; ++t)
#pragma unroll
            for (int r = 0; r < 8; ++r) acc[t][r] = 0.f;
        for (int i = 0; i < NN; ++i) {
            const size_t rowo = (size_t)i * NN + (size_t)j0;
#pragma unroll
            for (int r = 0; r < 8; ++r) {
                const float w = W[rowo + r];
                const int t = Ty[rowo + r];
                acc[0][r] += (t == 1) ? w : 0.f;
                acc[1][r] += (t == 2) ? w : 0.f;
                acc[2][r] += (t == 3) ? w : 0.f;
                acc[3][r] += (t == 4) ? w : 0.f;
                acc[4][r] += (t == 5) ? w : 0.f;
                acc[5][r] += (t == 6) ? w : 0.f;
            }
        }
#pragma unroll
        for (int t = 0; t < 6; ++t)
#pragma unroll
            for (int r = 0; r < 8; ++r)
                q[t][r] = 0.1f * s0[(size_t)t * NN + j0 + r] * acc[t][r];
    } else {
#pragma unroll
        for (int t = 0; t < 6; ++t)
#pragma unroll
            for (int r = 0; r < 8; ++r)
                q[t][r] = 0.1f * s0[(size_t)t * NN + j0 + r] *
                          colsg[(size_t)t * NN + j0 + r];
    }

    float V[8], m[8], h[8], n[8], Ie[8];
#pragma unroll
    for (int r = 0; r < 8; ++r) {
        V[r] = V0[j0 + r];
        m[r] = m0[j0 + r];
        h[r] = h0[j0 + r];
        n[r] = n0[j0 + r];
        Ie[r] = Iext[j0 + r];
    }

    __shared__ float wsum[2][8];
    __shared__ float Bsh[2];   // B_1, B_2 (types with E != 0)

    // ---- one-time block reduction of B1, B2 ----
    {
        float b1 = 0.f, b2 = 0.f;
#pragma unroll
        for (int r = 0; r < 8; ++r) { b1 += q[1][r]; b2 += q[2][r]; }
#pragma unroll
        for (int off = 32; off > 0; off >>= 1) {
            b1 += __shfl_down(b1, off);
            b2 += __shfl_down(b2, off);
        }
        if ((tid & 63) == 0) { wsum[0][tid >> 6] = b1; wsum[1][tid >> 6] = b2; }
        __syncthreads();
        if (tid == 0) {
            float s1 = 0.f, s2 = 0.f;
            for (int w2 = 0; w2 < 8; ++w2) { s1 += wsum[0][w2]; s2 += wsum[1][w2]; }
            Bsh[0] = s1; Bsh[1] = s2;
        }
        __syncthreads();
    }
    // correction constants: S = psum - sum_t sD_t*E_t*B_t ; E1=-70, E2=-90
    const float CE1 = -70.0f * Bsh[0];
    const float CE2 = -90.0f * Bsh[1];
    __syncthreads();

    for (int k = 0; k < steps; ++k) {
        // advance decay powers: step k uses dec^(k+1), sign pre-folded
#pragma unroll
        for (int t = 0; t < 6; ++t) sD[t] *= dec[t];

        // --- coupling partial: p = sum_r V_r * (sum_t sD_t * q_tr) ---
        float p = 0.f;
#pragma unroll
        for (int r = 0; r < 8; ++r) {
            float w = sD[5] * q[5][r];
            w = fmaf(sD[4], q[4][r], w);
            w = fmaf(sD[3], q[3][r], w);
            w = fmaf(sD[2], q[2][r], w);
            w = fmaf(sD[1], q[1][r], w);
            w = fmaf(sD[0], q[0][r], w);
            p = fmaf(w, V[r], p);
        }
#pragma unroll
        for (int off = 32; off > 0; off >>= 1) p += __shfl_down(p, off);
        const int par = k & 1;
        if ((tid & 63) == 0) wsum[par][tid >> 6] = p;
        __syncthreads();
        float psum = 0.f;
#pragma unroll
        for (int w2 = 0; w2 < 8; ++w2) psum += wsum[par][w2];
        const float S = psum - fmaf(sD[1], CE1, sD[2] * CE2);

        // --- per-neuron HH update (fast exp/rcp; inf/NaN flow preserved) ---
#pragma unroll
        for (int r = 0; r < 8; ++r) {
            const float v = V[r];
            const float Ipre = Ie[r] + S;
            const float a1 = 2.5f - 0.1f * v;
            const float am = a1 * __builtin_amdgcn_rcpf(__expf(a1) - 1.0f);
            const float bm = 4.0f * __expf(v * (-1.0f / 18.0f));
            const float ah = 0.07f * __expf(v * (-1.0f / 20.0f));
            const float bh = __builtin_amdgcn_rcpf(__expf(3.0f - 0.1f * v) + 1.0f);
            const float a5 = 0.1f - 0.01f * v;
            const float an = a5 * __builtin_amdgcn_rcpf(__expf(1.0f - 0.1f * v) - 1.0f);
            const float bn = 0.125f * __expf(v * (-1.0f / 80.0f));
            const float mm = m[r] + 0.01f * (am * (1.0f - m[r]) - bm * m[r]);
            const float hh = h[r] + 0.01f * (ah * (1.0f - h[r]) - bh * h[r]);
            const float nn = n[r] + 0.01f * (an * (1.0f - n[r]) - bn * n[r]);
            m[r] = mm; h[r] = hh; n[r] = nn;
            const float INa = ((120.0f * ((mm * mm) * mm)) * hh) * (v - 50.0f);
            const float n2 = nn * nn;
            const float IK = (36.0f * (n2 * n2)) * (v + 77.0f);
            const float IL = 0.3f * (v + 54.387f);
            const float u = v + 0.01f * (((Ipre - INa) - IK) - IL);
            // clip then nan_to_num: numpy clip propagates NaN -> 0
            V[r] = (u != u) ? 0.0f : fminf(fmaxf(u, -100.0f), 100.0f);
        }

        // --- write V_hist row k (two float4 per thread, coalesced) ---
        float4* o = (float4*)(out + (size_t)k * NN + j0);
        o[0] = make_float4(V[0], V[1], V[2], V[3]);
        o[1] = make_float4(V[4], V[5], V[6], V[7]);
    }
}

extern "C" void kernel_launch(void* const* d_in, const int* in_sizes, int n_in,
                              void* d_out, int out_size, void* d_ws, size_t ws_size,
                              hipStream_t stream)
{
    const float* Iext = (const float*)d_in[0];
    const float* W    = (const float*)d_in[1];
    const float* V0   = (const float*)d_in[2];
    const float* m0   = (const float*)d_in[3];
    const float* h0   = (const float*)d_in[4];
    const float* n0   = (const float*)d_in[5];
    const float* s0   = (const float*)d_in[6];
    const int*   Ty   = (const int*)d_in[7];
    const int*   Tp   = (const int*)d_in[8];
    float* out = (float*)d_out;
    float* ws  = (float*)d_ws;

    const size_t needCH64 = (size_t)(64 * 6 + 6) * NN * sizeof(float); // ~6.4 MB
    const size_t needCH8  = (size_t)(8 * 6 + 6) * NN * sizeof(float);  // ~864 KB
    const size_t needCH1  = (size_t)6 * NN * sizeof(float);            // 96 KB

    if (ws_size >= needCH64) {
        float* part = ws;
        float* cols = ws + (size_t)64 * 6 * NN;
        hipLaunchKernelGGL(col_partial_k, dim3(NN / 256, 64), dim3(256), 0, stream,
                           W, Ty, part, NN / 64);
        hipLaunchKernelGGL(col_reduce_k, dim3(6 * NN / 256), dim3(256), 0, stream,
                           part, cols, 64);
        hipLaunchKernelGGL(hh_sim_k, dim3(1), dim3(512), 0, stream,
                           Iext, V0, m0, h0, n0, s0, cols, Tp, W, Ty, 0, out);
    } else if (ws_size >= needCH8) {
        float* part = ws;
        float* cols = ws + (size_t)8 * 6 * NN;
        hipLaunchKernelGGL(col_partial_k, dim3(NN / 256, 8), dim3(256), 0, stream,
                           W, Ty, part, NN / 8);
        hipLaunchKernelGGL(col_reduce_k, dim3(6 * NN / 256), dim3(256), 0, stream,
                           part, cols, 8);
        hipLaunchKernelGGL(hh_sim_k, dim3(1), dim3(512), 0, stream,
                           Iext, V0, m0, h0, n0, s0, cols, Tp, W, Ty, 0, out);
    } else if (ws_size >= needCH1) {
        float* cols = ws;
        hipLaunchKernelGGL(col_partial_k, dim3(NN / 256, 1), dim3(256), 0, stream,
                           W, Ty, cols, NN);
        hipLaunchKernelGGL(hh_sim_k, dim3(1), dim3(512), 0, stream,
                           Iext, V0, m0, h0, n0, s0, cols, Tp, W, Ty, 0, out);
    } else {
        hipLaunchKernelGGL(hh_sim_k, dim3(1), dim3(512), 0, stream,
                           Iext, V0, m0, h0, n0, s0, (const float*)0, Tp, W, Ty, 1, out);
    }
}

// Round 3
// 2096.602 us; speedup vs baseline: 2.9854x; 1.0772x over previous
//
#include <hip/hip_runtime.h>
#include <math.h>

#define NN 4096

// ---------------- cols precompute: per-type masked column sums of W ----------
// part[(c*6+t)*NN + j] = sum over rows i in chunk c of W[i,j] where Ty[i,j]==t+1
// float4/int4 version: each thread owns 4 consecutive columns.
__global__ __launch_bounds__(256) void col_partial_k(
    const float* __restrict__ W, const int* __restrict__ Ty,
    float* __restrict__ part, int chunkRows)
{
    const int j4 = (blockIdx.x * 256 + threadIdx.x) * 4;
    const int c = blockIdx.y;
    const size_t i0 = (size_t)c * (size_t)chunkRows;
    float a[6][4];
#pragma unroll
    for (int t = 0; t < 6; ++t)
#pragma unroll
        for (int r = 0; r < 4; ++r) a[t][r] = 0.f;

#pragma unroll 2
    for (size_t i = i0; i < i0 + (size_t)chunkRows; ++i) {
        const size_t off = i * NN + j4;
        const float4 w = *(const float4*)(W + off);
        const int4 t = *(const int4*)(Ty + off);
        const float wv[4] = { w.x, w.y, w.z, w.w };
        const int tv[4] = { t.x, t.y, t.z, t.w };
#pragma unroll
        for (int r = 0; r < 4; ++r) {
            a[0][r] += (tv[r] == 1) ? wv[r] : 0.f;
            a[1][r] += (tv[r] == 2) ? wv[r] : 0.f;
            a[2][r] += (tv[r] == 3) ? wv[r] : 0.f;
            a[3][r] += (tv[r] == 4) ? wv[r] : 0.f;
            a[4][r] += (tv[r] == 5) ? wv[r] : 0.f;
            a[5][r] += (tv[r] == 6) ? wv[r] : 0.f;
        }
    }
    const size_t base = ((size_t)c * 6) * NN + (size_t)j4;
#pragma unroll
    for (int t = 0; t < 6; ++t)
        *(float4*)(part + base + (size_t)t * NN) =
            make_float4(a[t][0], a[t][1], a[t][2], a[t][3]);
}

__global__ __launch_bounds__(256) void col_reduce_k(
    const float* __restrict__ part, float* __restrict__ cols, int CH)
{
    const int idx = blockIdx.x * 256 + threadIdx.x; // t*NN + j
    float s = 0.f;
    for (int c = 0; c < CH; ++c) s += part[(size_t)c * 6 * NN + idx];
    cols[idx] = s;
}

// ---------------- main simulation: single workgroup, 1024 thr x 4 neurons ---
// s has NO V-dependence -> s_k = s0 * dec^(k+1).
// S(k) = sum_t sign_t * D_t * ( sum_j q_tj * V_j  -  E_t * B_t ),
//   q_tj = 0.1 * s0_tj * cols_tj   (per-thread constant),
//   D_t  = dec_t^(k+1)             (running scalar, sign pre-folded),
//   B_t  = sum_j q_tj              (block-reduced once; only t=1,2 have E!=0).
// Exp merging: exp(2.5-.1v), exp(3-.1v), exp(1-.1v) share X = exp(2.5-.1v):
//   exp(3-.1v) = e^{0.5} * X ; exp(1-.1v) = e^{-1.5} * X.
// NaN spots preserved: X-1==0 at v==25 (a1==0 -> 0*inf=NaN), e^{-1.5}X-1==0
// at v==10 (a5==0 -> NaN) — same as reference 0/0.
__global__ __launch_bounds__(1024) void hh_sim_k(
    const float* __restrict__ Iext, const float* __restrict__ V0,
    const float* __restrict__ m0, const float* __restrict__ h0,
    const float* __restrict__ n0, const float* __restrict__ s0,
    const float* __restrict__ colsg, const int* __restrict__ Tp,
    const float* __restrict__ W, const int* __restrict__ Ty,
    int computeCols, float* __restrict__ out)
{
#pragma clang fp contract(off)
    const int tid = threadIdx.x;      // 0..1023
    const int j0 = tid * 4;           // 4 contiguous neurons per thread
    const int steps = Tp[0] * 100;    // T / DT, DT = 0.01

    const float tau[6] = { 2.0f, 5.0f, 10.0f, 100.0f, 50.0f, 30.0f };
    const float sgn[6] = { -1.0f, 1.0f, 1.0f, -1.0f, -1.0f, -1.0f };
    float dec[6], sD[6];
#pragma unroll
    for (int t = 0; t < 6; ++t) { dec[t] = 1.0f - 0.01f / tau[t]; sD[t] = sgn[t]; }

    // ---- q = 0.1 * s0 * cols ----
    float q[6][4];
    if (computeCols) {
        float acc[6][4];
#pragma unroll
        for (int t = 0; t < 6; ++t)
#pragma unroll
            for (int r = 0; r < 4; ++r) acc[t][r] = 0.f;
        for (int i = 0; i < NN; ++i) {
            const size_t rowo = (size_t)i * NN + (size_t)j0;
#pragma unroll
            for (int r = 0; r < 4; ++r) {
                const float w = W[rowo + r];
                const int t = Ty[rowo + r];
                acc[0][r] += (t == 1) ? w : 0.f;
                acc[1][r] += (t == 2) ? w : 0.f;
                acc[2][r] += (t == 3) ? w : 0.f;
                acc[3][r] += (t == 4) ? w : 0.f;
                acc[4][r] += (t == 5) ? w : 0.f;
                acc[5][r] += (t == 6) ? w : 0.f;
            }
        }
#pragma unroll
        for (int t = 0; t < 6; ++t)
#pragma unroll
            for (int r = 0; r < 4; ++r)
                q[t][r] = 0.1f * s0[(size_t)t * NN + j0 + r] * acc[t][r];
    } else {
#pragma unroll
        for (int t = 0; t < 6; ++t)
#pragma unroll
            for (int r = 0; r < 4; ++r)
                q[t][r] = 0.1f * s0[(size_t)t * NN + j0 + r] *
                          colsg[(size_t)t * NN + j0 + r];
    }

    float V[4], m[4], h[4], n[4], Ie[4];
#pragma unroll
    for (int r = 0; r < 4; ++r) {
        V[r] = V0[j0 + r];
        m[r] = m0[j0 + r];
        h[r] = h0[j0 + r];
        n[r] = n0[j0 + r];
        Ie[r] = Iext[j0 + r];
    }

    __shared__ float wsum[2][16];
    __shared__ float Bsh[2];   // B_1, B_2 (types with E != 0)

    // ---- one-time block reduction of B1, B2 ----
    {
        float b1 = 0.f, b2 = 0.f;
#pragma unroll
        for (int r = 0; r < 4; ++r) { b1 += q[1][r]; b2 += q[2][r]; }
#pragma unroll
        for (int off = 32; off > 0; off >>= 1) {
            b1 += __shfl_down(b1, off);
            b2 += __shfl_down(b2, off);
        }
        if ((tid & 63) == 0) { wsum[0][tid >> 6] = b1; wsum[1][tid >> 6] = b2; }
        __syncthreads();
        if (tid == 0) {
            float s1 = 0.f, s2 = 0.f;
            for (int w2 = 0; w2 < 16; ++w2) { s1 += wsum[0][w2]; s2 += wsum[1][w2]; }
            Bsh[0] = s1; Bsh[1] = s2;
        }
        __syncthreads();
    }
    // correction constants: S = psum - sum_t sD_t*E_t*B_t ; E1=-70, E2=-90
    const float CE1 = -70.0f * Bsh[0];
    const float CE2 = -90.0f * Bsh[1];
    __syncthreads();

    for (int k = 0; k < steps; ++k) {
        // advance decay powers: step k uses dec^(k+1), sign pre-folded
#pragma unroll
        for (int t = 0; t < 6; ++t) sD[t] *= dec[t];

        // --- coupling partial: p = sum_r V_r * (sum_t sD_t * q_tr) ---
        float p = 0.f;
#pragma unroll
        for (int r = 0; r < 4; ++r) {
            float w = sD[5] * q[5][r];
            w = fmaf(sD[4], q[4][r], w);
            w = fmaf(sD[3], q[3][r], w);
            w = fmaf(sD[2], q[2][r], w);
            w = fmaf(sD[1], q[1][r], w);
            w = fmaf(sD[0], q[0][r], w);
            p = fmaf(w, V[r], p);
        }
#pragma unroll
        for (int off = 32; off > 0; off >>= 1) p += __shfl_down(p, off);
        const int par = k & 1;
        if ((tid & 63) == 0) wsum[par][tid >> 6] = p;
        __syncthreads();
        float psum = 0.f;
#pragma unroll
        for (int w2 = 0; w2 < 16; ++w2) psum += wsum[par][w2];
        const float S = psum - fmaf(sD[1], CE1, sD[2] * CE2);

        // --- per-neuron HH update (fast exp/rcp; inf/NaN flow preserved) ---
#pragma unroll
        for (int r = 0; r < 4; ++r) {
            const float v = V[r];
            const float Ipre = Ie[r] + S;
            const float a1 = 2.5f - 0.1f * v;
            const float X = __expf(a1);
            const float am = a1 * __builtin_amdgcn_rcpf(X - 1.0f);
            const float bm = 4.0f * __expf(v * (-1.0f / 18.0f));
            const float ah = 0.07f * __expf(v * (-1.0f / 20.0f));
            const float bh = __builtin_amdgcn_rcpf(
                fmaf(1.6487212707001281f, X, 1.0f));   // e^{0.5} X + 1
            const float a5 = 0.1f - 0.01f * v;
            const float an = a5 * __builtin_amdgcn_rcpf(
                fmaf(0.2231301601484298f, X, -1.0f));  // e^{-1.5} X - 1
            const float bn = 0.125f * __expf(v * (-1.0f / 80.0f));
            const float mm = m[r] + 0.01f * (am * (1.0f - m[r]) - bm * m[r]);
            const float hh = h[r] + 0.01f * (ah * (1.0f - h[r]) - bh * h[r]);
            const float nn = n[r] + 0.01f * (an * (1.0f - n[r]) - bn * n[r]);
            m[r] = mm; h[r] = hh; n[r] = nn;
            const float INa = ((120.0f * ((mm * mm) * mm)) * hh) * (v - 50.0f);
            const float n2 = nn * nn;
            const float IK = (36.0f * (n2 * n2)) * (v + 77.0f);
            const float IL = 0.3f * (v + 54.387f);
            const float u = v + 0.01f * (((Ipre - INa) - IK) - IL);
            // clip then nan_to_num: numpy clip propagates NaN -> 0
            V[r] = (u != u) ? 0.0f : fminf(fmaxf(u, -100.0f), 100.0f);
        }

        // --- write V_hist row k (one float4 per thread, coalesced) ---
        *(float4*)(out + (size_t)k * NN + j0) =
            make_float4(V[0], V[1], V[2], V[3]);
    }
}

extern "C" void kernel_launch(void* const* d_in, const int* in_sizes, int n_in,
                              void* d_out, int out_size, void* d_ws, size_t ws_size,
                              hipStream_t stream)
{
    const float* Iext = (const float*)d_in[0];
    const float* W    = (const float*)d_in[1];
    const float* V0   = (const float*)d_in[2];
    const float* m0   = (const float*)d_in[3];
    const float* h0   = (const float*)d_in[4];
    const float* n0   = (const float*)d_in[5];
    const float* s0   = (const float*)d_in[6];
    const int*   Ty   = (const int*)d_in[7];
    const int*   Tp   = (const int*)d_in[8];
    float* out = (float*)d_out;
    float* ws  = (float*)d_ws;

    // tiered workspace use: part[CH*6*NN] + cols[6*NN]
    const int tiers[3] = { 128, 64, 8 };
    int CH = 0;
    for (int i = 0; i < 3; ++i) {
        const size_t need = (size_t)(tiers[i] * 6 + 6) * NN * sizeof(float);
        if (ws_size >= need) { CH = tiers[i]; break; }
    }

    if (CH > 0) {
        float* part = ws;
        float* cols = ws + (size_t)CH * 6 * NN;
        hipLaunchKernelGGL(col_partial_k, dim3(NN / 1024, CH), dim3(256), 0, stream,
                           W, Ty, part, NN / CH);
        hipLaunchKernelGGL(col_reduce_k, dim3(6 * NN / 256), dim3(256), 0, stream,
                           part, cols, CH);
        hipLaunchKernelGGL(hh_sim_k, dim3(1), dim3(1024), 0, stream,
                           Iext, V0, m0, h0, n0, s0, cols, Tp, W, Ty, 0, out);
    } else if (ws_size >= (size_t)6 * NN * sizeof(float)) {
        float* cols = ws;
        hipLaunchKernelGGL(col_partial_k, dim3(NN / 1024, 1), dim3(256), 0, stream,
                           W, Ty, cols, NN);
        hipLaunchKernelGGL(hh_sim_k, dim3(1), dim3(1024), 0, stream,
                           Iext, V0, m0, h0, n0, s0, cols, Tp, W, Ty, 0, out);
    } else {
        hipLaunchKernelGGL(hh_sim_k, dim3(1), dim3(1024), 0, stream,
                           Iext, V0, m0, h0, n0, s0, (const float*)0, Tp, W, Ty, 1, out);
    }
}

// Round 4
// 1613.056 us; speedup vs baseline: 3.8804x; 1.2998x over previous
//
#include <hip/hip_runtime.h>
#include <math.h>

#define NN 4096
#define CBLK 8               // blocks (CUs) in the sim kernel
#define NPB (NN / CBLK)      // 512 neurons per block
#define TT (NPB + 64)        // 576 threads: wave0 coordinator + 8 compute waves

typedef unsigned long long ull;

// ---------------- cols precompute: per-type masked column sums of W ----------
__global__ __launch_bounds__(256) void col_partial_k(
    const float* __restrict__ W, const int* __restrict__ Ty,
    float* __restrict__ part, int chunkRows)
{
    const int j4 = (blockIdx.x * 256 + threadIdx.x) * 4;
    const int c = blockIdx.y;
    const size_t i0 = (size_t)c * (size_t)chunkRows;
    float a[6][4];
#pragma unroll
    for (int t = 0; t < 6; ++t)
#pragma unroll
        for (int r = 0; r < 4; ++r) a[t][r] = 0.f;

#pragma unroll 4
    for (size_t i = i0; i < i0 + (size_t)chunkRows; ++i) {
        const size_t off = i * NN + j4;
        const float4 w = *(const float4*)(W + off);
        const int4 t = *(const int4*)(Ty + off);
        const float wv[4] = { w.x, w.y, w.z, w.w };
        const int tv[4] = { t.x, t.y, t.z, t.w };
#pragma unroll
        for (int r = 0; r < 4; ++r) {
            a[0][r] += (tv[r] == 1) ? wv[r] : 0.f;
            a[1][r] += (tv[r] == 2) ? wv[r] : 0.f;
            a[2][r] += (tv[r] == 3) ? wv[r] : 0.f;
            a[3][r] += (tv[r] == 4) ? wv[r] : 0.f;
            a[4][r] += (tv[r] == 5) ? wv[r] : 0.f;
            a[5][r] += (tv[r] == 6) ? wv[r] : 0.f;
        }
    }
    const size_t base = ((size_t)c * 6) * NN + (size_t)j4;
#pragma unroll
    for (int t = 0; t < 6; ++t)
        *(float4*)(part + base + (size_t)t * NN) =
            make_float4(a[t][0], a[t][1], a[t][2], a[t][3]);
}

__global__ __launch_bounds__(256) void col_reduce_k(
    const float* __restrict__ part, float* __restrict__ cols, int CH)
{
    const int idx = blockIdx.x * 256 + threadIdx.x; // t*NN + j
    float s = 0.f;
    for (int c = 0; c < CH; ++c) s += part[(size_t)c * 6 * NN + idx];
    cols[idx] = s;
}

// ---------------- multi-CU simulation ---------------------------------------
// 8 blocks x 576 threads. Wave 0 of each block is the coordinator; waves 1..8
// own 64 neurons each (1/thread). Per step the only cross-block datum is the
// scalar S; each block publishes its (correction-folded) partial as a 64-bit
// word {tag=k+1, float bits} via relaxed agent-scope atomics (data rides in
// the word -> no fence needed). Parity double-buffer makes slot reuse safe:
// write(k+2) happens-after poll(k+1) happens-after all store(k+1)
// happens-after poll(k) reads of step-k slots.
// Gate math (V-only) overlaps the exchange; only u = v + 0.01*(base+S) waits.
__global__ __launch_bounds__(TT) void hh_sim_multi(
    const float* __restrict__ Iext, const float* __restrict__ V0,
    const float* __restrict__ m0, const float* __restrict__ h0,
    const float* __restrict__ n0, const float* __restrict__ s0,
    const float* __restrict__ cols, const int* __restrict__ Tp,
    ull* __restrict__ slots, float* __restrict__ out)
{
#pragma clang fp contract(off)
    const int tid = threadIdx.x;
    const int wave = tid >> 6;
    const int lane = tid & 63;
    const int b = blockIdx.x;
    const int steps = Tp[0] * 100;   // T / DT, DT = 0.01

    const float tau[6] = { 2.0f, 5.0f, 10.0f, 100.0f, 50.0f, 30.0f };
    const float sgn[6] = { -1.0f, 1.0f, 1.0f, -1.0f, -1.0f, -1.0f };
    float dec[6], sD[6];
#pragma unroll
    for (int t = 0; t < 6; ++t) { dec[t] = 1.0f - 0.01f / tau[t]; sD[t] = sgn[t]; }

    __shared__ float wpart[9];
    __shared__ float binit1[9], binit2[9];
    __shared__ float Ssh;

    // ---- per-thread state + block-local correction constants ----
    float V = 0.f, m = 0.f, h = 0.f, n = 0.f, Ie = 0.f, q[6];
#pragma unroll
    for (int t = 0; t < 6; ++t) q[t] = 0.f;
    int j = 0;
    if (wave >= 1) {
        j = b * NPB + (wave - 1) * 64 + lane;
        V = V0[j]; m = m0[j]; h = h0[j]; n = n0[j]; Ie = Iext[j];
#pragma unroll
        for (int t = 0; t < 6; ++t)
            q[t] = 0.1f * s0[(size_t)t * NN + j] * cols[(size_t)t * NN + j];
        float b1 = q[1], b2 = q[2];
#pragma unroll
        for (int off = 32; off > 0; off >>= 1) {
            b1 += __shfl_down(b1, off);
            b2 += __shfl_down(b2, off);
        }
        if (lane == 0) { binit1[wave] = b1; binit2[wave] = b2; }
    }
    __syncthreads();
    // wave0 lane0 keeps CE1/CE2; f1/f2 track +dec^(k+1) for types 1,2
    float CE1 = 0.f, CE2 = 0.f, f1 = 1.0f, f2 = 1.0f;
    if (wave == 0 && lane == 0) {
        float s1 = 0.f, s2 = 0.f;
        for (int w2 = 1; w2 <= 8; ++w2) { s1 += binit1[w2]; s2 += binit2[w2]; }
        CE1 = -70.0f * s1;   // E1 * B1_block
        CE2 = -90.0f * s2;   // E2 * B2_block
    }
    __syncthreads();

    for (int k = 0; k < steps; ++k) {
        // --- coupling partial (compute waves) / decay advance (wave0) ---
        if (wave >= 1) {
#pragma unroll
            for (int t = 0; t < 6; ++t) sD[t] *= dec[t];
            float w6 = sD[5] * q[5];
            w6 = fmaf(sD[4], q[4], w6);
            w6 = fmaf(sD[3], q[3], w6);
            w6 = fmaf(sD[2], q[2], w6);
            w6 = fmaf(sD[1], q[1], w6);
            w6 = fmaf(sD[0], q[0], w6);
            float x = w6 * V;
#pragma unroll
            for (int off = 32; off > 0; off >>= 1) x += __shfl_down(x, off);
            if (lane == 0) wpart[wave] = x;
        } else {
            f1 *= dec[1]; f2 *= dec[2];
        }
        __syncthreads();   // #1: wpart ready

        float base = 0.f;
        if (wave >= 1) {
            // --- gate math: depends only on V, overlaps the S exchange ---
            const float v = V;
            const float a1 = 2.5f - 0.1f * v;
            const float X = __expf(a1);
            const float am = a1 * __builtin_amdgcn_rcpf(X - 1.0f);
            const float bm = 4.0f * __expf(v * (-1.0f / 18.0f));
            const float ah = 0.07f * __expf(v * (-1.0f / 20.0f));
            const float bh = __builtin_amdgcn_rcpf(
                fmaf(1.6487212707001281f, X, 1.0f));   // e^{0.5} X + 1
            const float a5 = 0.1f - 0.01f * v;
            const float an = a5 * __builtin_amdgcn_rcpf(
                fmaf(0.2231301601484298f, X, -1.0f));  // e^{-1.5} X - 1
            const float bn = 0.125f * __expf(v * (-1.0f / 80.0f));
            const float mm = m + 0.01f * (am * (1.0f - m) - bm * m);
            const float hh = h + 0.01f * (ah * (1.0f - h) - bh * h);
            const float nn = n + 0.01f * (an * (1.0f - n) - bn * n);
            m = mm; h = hh; n = nn;
            const float INa = ((120.0f * ((mm * mm) * mm)) * hh) * (v - 50.0f);
            const float n2 = nn * nn;
            const float IK = (36.0f * (n2 * n2)) * (v + 77.0f);
            const float IL = 0.3f * (v + 54.387f);
            base = ((Ie - INa) - IK) - IL;
        } else if (lane < 8) {
            // --- coordinator: block sum, publish, gather, total ---
            float p = wpart[1 + lane];
            p += __shfl_down(p, 4);
            p += __shfl_down(p, 2);
            p += __shfl_down(p, 1);
            const unsigned tag = (unsigned)(k + 1);
            const int par = (k & 1) * CBLK;
            if (lane == 0) {
                p = p - fmaf(f1, CE1, f2 * CE2);
                const ull packed = ((ull)tag << 32) | (ull)__float_as_uint(p);
                __hip_atomic_store(&slots[par + b], packed,
                                   __ATOMIC_RELAXED, __HIP_MEMORY_SCOPE_AGENT);
            }
            ull got;
            do {
                got = __hip_atomic_load(&slots[par + lane],
                                        __ATOMIC_RELAXED, __HIP_MEMORY_SCOPE_AGENT);
            } while ((unsigned)(got >> 32) != tag);
            float val = __uint_as_float((unsigned)got);
            val += __shfl_down(val, 4);
            val += __shfl_down(val, 2);
            val += __shfl_down(val, 1);
            if (lane == 0) Ssh = val;
        }
        __syncthreads();   // #2: Ssh ready

        if (wave >= 1) {
            const float S = Ssh;
            const float u = V + 0.01f * (base + S);
            // clip then nan_to_num: numpy clip propagates NaN -> 0
            V = (u != u) ? 0.0f : fminf(fmaxf(u, -100.0f), 100.0f);
            out[(size_t)k * NN + j] = V;
        }
    }
}

// ---------------- single-block fallback (tiny workspace) --------------------
__global__ __launch_bounds__(1024) void hh_sim_single(
    const float* __restrict__ Iext, const float* __restrict__ V0,
    const float* __restrict__ m0, const float* __restrict__ h0,
    const float* __restrict__ n0, const float* __restrict__ s0,
    const float* __restrict__ colsg, const int* __restrict__ Tp,
    const float* __restrict__ W, const int* __restrict__ Ty,
    int computeCols, float* __restrict__ out)
{
#pragma clang fp contract(off)
    const int tid = threadIdx.x;
    const int j0 = tid * 4;
    const int steps = Tp[0] * 100;

    const float tau[6] = { 2.0f, 5.0f, 10.0f, 100.0f, 50.0f, 30.0f };
    const float sgn[6] = { -1.0f, 1.0f, 1.0f, -1.0f, -1.0f, -1.0f };
    float dec[6], sD[6];
#pragma unroll
    for (int t = 0; t < 6; ++t) { dec[t] = 1.0f - 0.01f / tau[t]; sD[t] = sgn[t]; }

    float q[6][4];
    if (computeCols) {
        float acc[6][4];
#pragma unroll
        for (int t = 0; t < 6; ++t)
#pragma unroll
            for (int r = 0; r < 4; ++r) acc[t][r] = 0.f;
        for (int i = 0; i < NN; ++i) {
            const size_t rowo = (size_t)i * NN + (size_t)j0;
#pragma unroll
            for (int r = 0; r < 4; ++r) {
                const float w = W[rowo + r];
                const int t = Ty[rowo + r];
                acc[0][r] += (t == 1) ? w : 0.f;
                acc[1][r] += (t == 2) ? w : 0.f;
                acc[2][r] += (t == 3) ? w : 0.f;
                acc[3][r] += (t == 4) ? w : 0.f;
                acc[4][r] += (t == 5) ? w : 0.f;
                acc[5][r] += (t == 6) ? w : 0.f;
            }
        }
#pragma unroll
        for (int t = 0; t < 6; ++t)
#pragma unroll
            for (int r = 0; r < 4; ++r)
                q[t][r] = 0.1f * s0[(size_t)t * NN + j0 + r] * acc[t][r];
    } else {
#pragma unroll
        for (int t = 0; t < 6; ++t)
#pragma unroll
            for (int r = 0; r < 4; ++r)
                q[t][r] = 0.1f * s0[(size_t)t * NN + j0 + r] *
                          colsg[(size_t)t * NN + j0 + r];
    }

    float V[4], m[4], h[4], n[4], Ie[4];
#pragma unroll
    for (int r = 0; r < 4; ++r) {
        V[r] = V0[j0 + r]; m[r] = m0[j0 + r]; h[r] = h0[j0 + r];
        n[r] = n0[j0 + r]; Ie[r] = Iext[j0 + r];
    }

    __shared__ float wsum[2][16];
    __shared__ float Bsh[2];
    {
        float b1 = 0.f, b2 = 0.f;
#pragma unroll
        for (int r = 0; r < 4; ++r) { b1 += q[1][r]; b2 += q[2][r]; }
#pragma unroll
        for (int off = 32; off > 0; off >>= 1) {
            b1 += __shfl_down(b1, off);
            b2 += __shfl_down(b2, off);
        }
        if ((tid & 63) == 0) { wsum[0][tid >> 6] = b1; wsum[1][tid >> 6] = b2; }
        __syncthreads();
        if (tid == 0) {
            float s1 = 0.f, s2 = 0.f;
            for (int w2 = 0; w2 < 16; ++w2) { s1 += wsum[0][w2]; s2 += wsum[1][w2]; }
            Bsh[0] = s1; Bsh[1] = s2;
        }
        __syncthreads();
    }
    const float CE1 = -70.0f * Bsh[0];
    const float CE2 = -90.0f * Bsh[1];
    __syncthreads();

    for (int k = 0; k < steps; ++k) {
#pragma unroll
        for (int t = 0; t < 6; ++t) sD[t] *= dec[t];
        float p = 0.f;
#pragma unroll
        for (int r = 0; r < 4; ++r) {
            float w = sD[5] * q[5][r];
            w = fmaf(sD[4], q[4][r], w);
            w = fmaf(sD[3], q[3][r], w);
            w = fmaf(sD[2], q[2][r], w);
            w = fmaf(sD[1], q[1][r], w);
            w = fmaf(sD[0], q[0][r], w);
            p = fmaf(w, V[r], p);
        }
#pragma unroll
        for (int off = 32; off > 0; off >>= 1) p += __shfl_down(p, off);
        const int par = k & 1;
        if ((tid & 63) == 0) wsum[par][tid >> 6] = p;
        __syncthreads();
        float psum = 0.f;
#pragma unroll
        for (int w2 = 0; w2 < 16; ++w2) psum += wsum[par][w2];
        const float S = psum - fmaf(sD[1], CE1, sD[2] * CE2);

#pragma unroll
        for (int r = 0; r < 4; ++r) {
            const float v = V[r];
            const float Ipre = Ie[r] + S;
            const float a1 = 2.5f - 0.1f * v;
            const float X = __expf(a1);
            const float am = a1 * __builtin_amdgcn_rcpf(X - 1.0f);
            const float bm = 4.0f * __expf(v * (-1.0f / 18.0f));
            const float ah = 0.07f * __expf(v * (-1.0f / 20.0f));
            const float bh = __builtin_amdgcn_rcpf(fmaf(1.6487212707001281f, X, 1.0f));
            const float a5 = 0.1f - 0.01f * v;
            const float an = a5 * __builtin_amdgcn_rcpf(fmaf(0.2231301601484298f, X, -1.0f));
            const float bn = 0.125f * __expf(v * (-1.0f / 80.0f));
            const float mm = m[r] + 0.01f * (am * (1.0f - m[r]) - bm * m[r]);
            const float hh = h[r] + 0.01f * (ah * (1.0f - h[r]) - bh * h[r]);
            const float nn = n[r] + 0.01f * (an * (1.0f - n[r]) - bn * n[r]);
            m[r] = mm; h[r] = hh; n[r] = nn;
            const float INa = ((120.0f * ((mm * mm) * mm)) * hh) * (v - 50.0f);
            const float n2 = nn * nn;
            const float IK = (36.0f * (n2 * n2)) * (v + 77.0f);
            const float IL = 0.3f * (v + 54.387f);
            const float u = v + 0.01f * (((Ipre - INa) - IK) - IL);
            V[r] = (u != u) ? 0.0f : fminf(fmaxf(u, -100.0f), 100.0f);
        }
        *(float4*)(out + (size_t)k * NN + j0) =
            make_float4(V[0], V[1], V[2], V[3]);
    }
}

extern "C" void kernel_launch(void* const* d_in, const int* in_sizes, int n_in,
                              void* d_out, int out_size, void* d_ws, size_t ws_size,
                              hipStream_t stream)
{
    const float* Iext = (const float*)d_in[0];
    const float* W    = (const float*)d_in[1];
    const float* V0   = (const float*)d_in[2];
    const float* m0   = (const float*)d_in[3];
    const float* h0   = (const float*)d_in[4];
    const float* n0   = (const float*)d_in[5];
    const float* s0   = (const float*)d_in[6];
    const int*   Ty   = (const int*)d_in[7];
    const int*   Tp   = (const int*)d_in[8];
    float* out = (float*)d_out;

    // ws layout: [slots: 2*CBLK ull = 128 B][cols 6*NN f32][part CH*6*NN f32]
    const size_t HDR = 128;
    ull*   slots = (ull*)d_ws;
    float* cols  = (float*)((char*)d_ws + HDR);
    float* part  = cols + (size_t)6 * NN;

    int CH = 0;
    const int tiers[2] = { 64, 8 };
    for (int i = 0; i < 2; ++i) {
        const size_t need = HDR + (size_t)(tiers[i] * 6 + 6) * NN * sizeof(float);
        if (ws_size >= need) { CH = tiers[i]; break; }
    }
    if (CH == 0 && ws_size >= HDR + (size_t)6 * NN * sizeof(float)) CH = 1;

    if (CH > 1) {
        hipLaunchKernelGGL(col_partial_k, dim3(NN / 1024, CH), dim3(256), 0, stream,
                           W, Ty, part, NN / CH);
        hipLaunchKernelGGL(col_reduce_k, dim3(6 * NN / 256), dim3(256), 0, stream,
                           part, cols, CH);
        hipLaunchKernelGGL(hh_sim_multi, dim3(CBLK), dim3(TT), 0, stream,
                           Iext, V0, m0, h0, n0, s0, cols, Tp, slots, out);
    } else if (CH == 1) {
        hipLaunchKernelGGL(col_partial_k, dim3(NN / 1024, 1), dim3(256), 0, stream,
                           W, Ty, cols, NN);
        hipLaunchKernelGGL(hh_sim_multi, dim3(CBLK), dim3(TT), 0, stream,
                           Iext, V0, m0, h0, n0, s0, cols, Tp, slots, out);
    } else {
        // pathological tiny workspace: single-block kernel computes cols itself
        hipLaunchKernelGGL(hh_sim_single, dim3(1), dim3(1024), 0, stream,
                           Iext, V0, m0, h0, n0, s0, (const float*)0, Tp, W, Ty, 1, out);
    }
}

// Round 5
// 1605.908 us; speedup vs baseline: 3.8976x; 1.0045x over previous
//
#include <hip/hip_runtime.h>
#include <math.h>

#define NN 4096
#define CBLK 8               // blocks (CUs) in the sim kernel
#define NPB (NN / CBLK)      // 512 neurons per block
#define SLOT_STRIDE 16       // ulls per slot line: 128 B -> one line per block

typedef unsigned long long ull;

// ---------------- cols precompute: per-type masked column sums of W ----------
__global__ __launch_bounds__(256) void col_partial_k(
    const float* __restrict__ W, const int* __restrict__ Ty,
    float* __restrict__ part, int chunkRows)
{
    const int j4 = (blockIdx.x * 256 + threadIdx.x) * 4;
    const int c = blockIdx.y;
    const size_t i0 = (size_t)c * (size_t)chunkRows;
    float a[6][4];
#pragma unroll
    for (int t = 0; t < 6; ++t)
#pragma unroll
        for (int r = 0; r < 4; ++r) a[t][r] = 0.f;

#pragma unroll 4
    for (size_t i = i0; i < i0 + (size_t)chunkRows; ++i) {
        const size_t off = i * NN + j4;
        const float4 w = *(const float4*)(W + off);
        const int4 t = *(const int4*)(Ty + off);
        const float wv[4] = { w.x, w.y, w.z, w.w };
        const int tv[4] = { t.x, t.y, t.z, t.w };
#pragma unroll
        for (int r = 0; r < 4; ++r) {
            a[0][r] += (tv[r] == 1) ? wv[r] : 0.f;
            a[1][r] += (tv[r] == 2) ? wv[r] : 0.f;
            a[2][r] += (tv[r] == 3) ? wv[r] : 0.f;
            a[3][r] += (tv[r] == 4) ? wv[r] : 0.f;
            a[4][r] += (tv[r] == 5) ? wv[r] : 0.f;
            a[5][r] += (tv[r] == 6) ? wv[r] : 0.f;
        }
    }
    const size_t base = ((size_t)c * 6) * NN + (size_t)j4;
#pragma unroll
    for (int t = 0; t < 6; ++t)
        *(float4*)(part + base + (size_t)t * NN) =
            make_float4(a[t][0], a[t][1], a[t][2], a[t][3]);
}

__global__ __launch_bounds__(256) void col_reduce_k(
    const float* __restrict__ part, float* __restrict__ cols, int CH)
{
    const int idx = blockIdx.x * 256 + threadIdx.x; // t*NN + j
    float s = 0.f;
    for (int c = 0; c < CH; ++c) s += part[(size_t)c * 6 * NN + idx];
    cols[idx] = s;
}

// ---------------- multi-CU simulation ---------------------------------------
// 8 blocks x 512 threads (8 waves, all compute). Per step the only cross-block
// datum is the scalar S. Each block's wave0 publishes the block partial as a
// 64-bit {tag=k+1, float} word into its OWN 128-B line (no false sharing);
// every wave polls all 8 lines itself (lanes 0..7) and reduces in-register --
// no second barrier, no coordinator wave. Parity double-buffer + tag makes
// slot reuse safe: block B's overwrite at step k+2 happens-after B's poll of
// step k+1, which requires A's publish of k+1, which happens-after A's waves
// all passed their step-k polls. Poisoned slots (0xAA..) never match any tag.
__global__ __launch_bounds__(NPB) void hh_sim_multi(
    const float* __restrict__ Iext, const float* __restrict__ V0,
    const float* __restrict__ m0, const float* __restrict__ h0,
    const float* __restrict__ n0, const float* __restrict__ s0,
    const float* __restrict__ cols, const int* __restrict__ Tp,
    ull* __restrict__ slots, float* __restrict__ out)
{
#pragma clang fp contract(off)
    const int tid = threadIdx.x;     // 0..511
    const int wave = tid >> 6;       // 0..7
    const int lane = tid & 63;
    const int b = blockIdx.x;
    const int steps = Tp[0] * 100;   // T / DT, DT = 0.01
    const int j = b * NPB + tid;     // this thread's neuron

    const float tau[6] = { 2.0f, 5.0f, 10.0f, 100.0f, 50.0f, 30.0f };
    const float sgn[6] = { -1.0f, 1.0f, 1.0f, -1.0f, -1.0f, -1.0f };
    float dec[6], sD[6];
#pragma unroll
    for (int t = 0; t < 6; ++t) { dec[t] = 1.0f - 0.01f / tau[t]; sD[t] = sgn[t]; }

    __shared__ float wpart[8];
    __shared__ float binit1[8], binit2[8];

    // ---- per-thread state ----
    float V = V0[j], m = m0[j], h = h0[j], n = n0[j], Ie = Iext[j];
    float q[6];
#pragma unroll
    for (int t = 0; t < 6; ++t)
        q[t] = 0.1f * s0[(size_t)t * NN + j] * cols[(size_t)t * NN + j];

    // ---- block-local correction constants (wave0 lane0 keeps them) ----
    {
        float b1 = q[1], b2 = q[2];
#pragma unroll
        for (int off = 32; off > 0; off >>= 1) {
            b1 += __shfl_down(b1, off);
            b2 += __shfl_down(b2, off);
        }
        if (lane == 0) { binit1[wave] = b1; binit2[wave] = b2; }
    }
    __syncthreads();
    float CE1 = 0.f, CE2 = 0.f;
    if (wave == 0 && lane == 0) {
        float s1 = 0.f, s2 = 0.f;
#pragma unroll
        for (int w2 = 0; w2 < 8; ++w2) { s1 += binit1[w2]; s2 += binit2[w2]; }
        CE1 = -70.0f * s1;   // E1 * B1_block   (sgn[1]=+1 -> factor = sD[1])
        CE2 = -90.0f * s2;   // E2 * B2_block   (sgn[2]=+1 -> factor = sD[2])
    }
    __syncthreads();

    for (int k = 0; k < steps; ++k) {
        // --- advance decay powers; coupling partial ---
#pragma unroll
        for (int t = 0; t < 6; ++t) sD[t] *= dec[t];
        float w6 = sD[5] * q[5];
        w6 = fmaf(sD[4], q[4], w6);
        w6 = fmaf(sD[3], q[3], w6);
        w6 = fmaf(sD[2], q[2], w6);
        w6 = fmaf(sD[1], q[1], w6);
        w6 = fmaf(sD[0], q[0], w6);
        float x = w6 * V;
#pragma unroll
        for (int off = 32; off > 0; off >>= 1) x += __shfl_down(x, off);
        if (lane == 0) wpart[wave] = x;
        __syncthreads();   // the ONLY barrier per step

        const unsigned tag = (unsigned)(k + 1);
        const int par = (k & 1) * CBLK;

        // --- wave0: block sum + publish to this block's own 128-B line ---
        if (wave == 0) {
            float p = (lane < 8) ? wpart[lane] : 0.f;
            p += __shfl_down(p, 4);
            p += __shfl_down(p, 2);
            p += __shfl_down(p, 1);
            if (lane == 0) {
                p = p - fmaf(sD[1], CE1, sD[2] * CE2);
                const ull packed = ((ull)tag << 32) | (ull)__float_as_uint(p);
                __hip_atomic_store(&slots[(size_t)(par + b) * SLOT_STRIDE], packed,
                                   __ATOMIC_RELAXED, __HIP_MEMORY_SCOPE_AGENT);
            }
        }

        // --- gate math: V-only, overlaps the exchange latency ---
        const float v = V;
        const float a1 = 2.5f - 0.1f * v;
        const float X = __expf(a1);
        const float am = a1 * __builtin_amdgcn_rcpf(X - 1.0f);
        const float bm = 4.0f * __expf(v * (-1.0f / 18.0f));
        const float ah = 0.07f * __expf(v * (-1.0f / 20.0f));
        const float bh = __builtin_amdgcn_rcpf(
            fmaf(1.6487212707001281f, X, 1.0f));   // e^{0.5} X + 1
        const float a5 = 0.1f - 0.01f * v;
        const float an = a5 * __builtin_amdgcn_rcpf(
            fmaf(0.2231301601484298f, X, -1.0f));  // e^{-1.5} X - 1
        const float bn = 0.125f * __expf(v * (-1.0f / 80.0f));
        const float mm = m + 0.01f * (am * (1.0f - m) - bm * m);
        const float hh = h + 0.01f * (ah * (1.0f - h) - bh * h);
        const float nn = n + 0.01f * (an * (1.0f - n) - bn * n);
        m = mm; h = hh; n = nn;
        const float INa = ((120.0f * ((mm * mm) * mm)) * hh) * (v - 50.0f);
        const float n2 = nn * nn;
        const float IK = (36.0f * (n2 * n2)) * (v + 77.0f);
        const float IL = 0.3f * (v + 54.387f);
        const float base = ((Ie - INa) - IK) - IL;

        // --- every wave polls the 8 lines itself; reduce in-register ---
        ull got = 0;
        if (lane < 8) {
            do {
                got = __hip_atomic_load(&slots[(size_t)(par + lane) * SLOT_STRIDE],
                                        __ATOMIC_RELAXED, __HIP_MEMORY_SCOPE_AGENT);
            } while ((unsigned)(got >> 32) != tag);
        }
        float val = (lane < 8) ? __uint_as_float((unsigned)got) : 0.f;
        val += __shfl_down(val, 4);
        val += __shfl_down(val, 2);
        val += __shfl_down(val, 1);
        const float S = __shfl(val, 0);

        // --- V update + history write ---
        const float u = V + 0.01f * (base + S);
        // clip then nan_to_num: numpy clip propagates NaN -> 0
        V = (u != u) ? 0.0f : fminf(fmaxf(u, -100.0f), 100.0f);
        out[(size_t)k * NN + j] = V;
    }
}

// ---------------- single-block fallback (tiny workspace) --------------------
__global__ __launch_bounds__(1024) void hh_sim_single(
    const float* __restrict__ Iext, const float* __restrict__ V0,
    const float* __restrict__ m0, const float* __restrict__ h0,
    const float* __restrict__ n0, const float* __restrict__ s0,
    const float* __restrict__ colsg, const int* __restrict__ Tp,
    const float* __restrict__ W, const int* __restrict__ Ty,
    int computeCols, float* __restrict__ out)
{
#pragma clang fp contract(off)
    const int tid = threadIdx.x;
    const int j0 = tid * 4;
    const int steps = Tp[0] * 100;

    const float tau[6] = { 2.0f, 5.0f, 10.0f, 100.0f, 50.0f, 30.0f };
    const float sgn[6] = { -1.0f, 1.0f, 1.0f, -1.0f, -1.0f, -1.0f };
    float dec[6], sD[6];
#pragma unroll
    for (int t = 0; t < 6; ++t) { dec[t] = 1.0f - 0.01f / tau[t]; sD[t] = sgn[t]; }

    float q[6][4];
    if (computeCols) {
        float acc[6][4];
#pragma unroll
        for (int t = 0; t < 6; ++t)
#pragma unroll
            for (int r = 0; r < 4; ++r) acc[t][r] = 0.f;
        for (int i = 0; i < NN; ++i) {
            const size_t rowo = (size_t)i * NN + (size_t)j0;
#pragma unroll
            for (int r = 0; r < 4; ++r) {
                const float w = W[rowo + r];
                const int t = Ty[rowo + r];
                acc[0][r] += (t == 1) ? w : 0.f;
                acc[1][r] += (t == 2) ? w : 0.f;
                acc[2][r] += (t == 3) ? w : 0.f;
                acc[3][r] += (t == 4) ? w : 0.f;
                acc[4][r] += (t == 5) ? w : 0.f;
                acc[5][r] += (t == 6) ? w : 0.f;
            }
        }
#pragma unroll
        for (int t = 0; t < 6; ++t)
#pragma unroll
            for (int r = 0; r < 4; ++r)
                q[t][r] = 0.1f * s0[(size_t)t * NN + j0 + r] * acc[t][r];
    } else {
#pragma unroll
        for (int t = 0; t < 6; ++t)
#pragma unroll
            for (int r = 0; r < 4; ++r)
                q[t][r] = 0.1f * s0[(size_t)t * NN + j0 + r] *
                          colsg[(size_t)t * NN + j0 + r];
    }

    float V[4], m[4], h[4], n[4], Ie[4];
#pragma unroll
    for (int r = 0; r < 4; ++r) {
        V[r] = V0[j0 + r]; m[r] = m0[j0 + r]; h[r] = h0[j0 + r];
        n[r] = n0[j0 + r]; Ie[r] = Iext[j0 + r];
    }

    __shared__ float wsum[2][16];
    __shared__ float Bsh[2];
    {
        float b1 = 0.f, b2 = 0.f;
#pragma unroll
        for (int r = 0; r < 4; ++r) { b1 += q[1][r]; b2 += q[2][r]; }
#pragma unroll
        for (int off = 32; off > 0; off >>= 1) {
            b1 += __shfl_down(b1, off);
            b2 += __shfl_down(b2, off);
        }
        if ((tid & 63) == 0) { wsum[0][tid >> 6] = b1; wsum[1][tid >> 6] = b2; }
        __syncthreads();
        if (tid == 0) {
            float s1 = 0.f, s2 = 0.f;
            for (int w2 = 0; w2 < 16; ++w2) { s1 += wsum[0][w2]; s2 += wsum[1][w2]; }
            Bsh[0] = s1; Bsh[1] = s2;
        }
        __syncthreads();
    }
    const float CE1 = -70.0f * Bsh[0];
    const float CE2 = -90.0f * Bsh[1];
    __syncthreads();

    for (int k = 0; k < steps; ++k) {
#pragma unroll
        for (int t = 0; t < 6; ++t) sD[t] *= dec[t];
        float p = 0.f;
#pragma unroll
        for (int r = 0; r < 4; ++r) {
            float w = sD[5] * q[5][r];
            w = fmaf(sD[4], q[4][r], w);
            w = fmaf(sD[3], q[3][r], w);
            w = fmaf(sD[2], q[2][r], w);
            w = fmaf(sD[1], q[1][r], w);
            w = fmaf(sD[0], q[0][r], w);
            p = fmaf(w, V[r], p);
        }
#pragma unroll
        for (int off = 32; off > 0; off >>= 1) p += __shfl_down(p, off);
        const int par = k & 1;
        if ((tid & 63) == 0) wsum[par][tid >> 6] = p;
        __syncthreads();
        float psum = 0.f;
#pragma unroll
        for (int w2 = 0; w2 < 16; ++w2) psum += wsum[par][w2];
        const float S = psum - fmaf(sD[1], CE1, sD[2] * CE2);

#pragma unroll
        for (int r = 0; r < 4; ++r) {
            const float v = V[r];
            const float Ipre = Ie[r] + S;
            const float a1 = 2.5f - 0.1f * v;
            const float X = __expf(a1);
            const float am = a1 * __builtin_amdgcn_rcpf(X - 1.0f);
            const float bm = 4.0f * __expf(v * (-1.0f / 18.0f));
            const float ah = 0.07f * __expf(v * (-1.0f / 20.0f));
            const float bh = __builtin_amdgcn_rcpf(fmaf(1.6487212707001281f, X, 1.0f));
            const float a5 = 0.1f - 0.01f * v;
            const float an = a5 * __builtin_amdgcn_rcpf(fmaf(0.2231301601484298f, X, -1.0f));
            const float bn = 0.125f * __expf(v * (-1.0f / 80.0f));
            const float mm = m[r] + 0.01f * (am * (1.0f - m[r]) - bm * m[r]);
            const float hh = h[r] + 0.01f * (ah * (1.0f - h[r]) - bh * h[r]);
            const float nn = n[r] + 0.01f * (an * (1.0f - n[r]) - bn * n[r]);
            m[r] = mm; h[r] = hh; n[r] = nn;
            const float INa = ((120.0f * ((mm * mm) * mm)) * hh) * (v - 50.0f);
            const float n2 = nn * nn;
            const float IK = (36.0f * (n2 * n2)) * (v + 77.0f);
            const float IL = 0.3f * (v + 54.387f);
            const float u = v + 0.01f * (((Ipre - INa) - IK) - IL);
            V[r] = (u != u) ? 0.0f : fminf(fmaxf(u, -100.0f), 100.0f);
        }
        *(float4*)(out + (size_t)k * NN + j0) =
            make_float4(V[0], V[1], V[2], V[3]);
    }
}

extern "C" void kernel_launch(void* const* d_in, const int* in_sizes, int n_in,
                              void* d_out, int out_size, void* d_ws, size_t ws_size,
                              hipStream_t stream)
{
    const float* Iext = (const float*)d_in[0];
    const float* W    = (const float*)d_in[1];
    const float* V0   = (const float*)d_in[2];
    const float* m0   = (const float*)d_in[3];
    const float* h0   = (const float*)d_in[4];
    const float* n0   = (const float*)d_in[5];
    const float* s0   = (const float*)d_in[6];
    const int*   Ty   = (const int*)d_in[7];
    const int*   Tp   = (const int*)d_in[8];
    float* out = (float*)d_out;

    // ws layout: [slots: 2*CBLK lines x 128 B = 2048 B][cols 6*NN][part CH*6*NN]
    const size_t HDR = 2 * CBLK * SLOT_STRIDE * sizeof(ull); // 2048 B
    ull*   slots = (ull*)d_ws;
    float* cols  = (float*)((char*)d_ws + HDR);
    float* part  = cols + (size_t)6 * NN;

    int CH = 0;
    const int tiers[2] = { 64, 8 };
    for (int i = 0; i < 2; ++i) {
        const size_t need = HDR + (size_t)(tiers[i] * 6 + 6) * NN * sizeof(float);
        if (ws_size >= need) { CH = tiers[i]; break; }
    }
    if (CH == 0 && ws_size >= HDR + (size_t)6 * NN * sizeof(float)) CH = 1;

    if (CH > 1) {
        hipLaunchKernelGGL(col_partial_k, dim3(NN / 1024, CH), dim3(256), 0, stream,
                           W, Ty, part, NN / CH);
        hipLaunchKernelGGL(col_reduce_k, dim3(6 * NN / 256), dim3(256), 0, stream,
                           part, cols, CH);
        hipLaunchKernelGGL(hh_sim_multi, dim3(CBLK), dim3(NPB), 0, stream,
                           Iext, V0, m0, h0, n0, s0, cols, Tp, slots, out);
    } else if (CH == 1) {
        hipLaunchKernelGGL(col_partial_k, dim3(NN / 1024, 1), dim3(256), 0, stream,
                           W, Ty, cols, NN);
        hipLaunchKernelGGL(hh_sim_multi, dim3(CBLK), dim3(NPB), 0, stream,
                           Iext, V0, m0, h0, n0, s0, cols, Tp, slots, out);
    } else {
        // pathological tiny workspace: single-block kernel computes cols itself
        hipLaunchKernelGGL(hh_sim_single, dim3(1), dim3(1024), 0, stream,
                           Iext, V0, m0, h0, n0, s0, (const float*)0, Tp, W, Ty, 1, out);
    }
}